// Round 9
// baseline (591.673 us; speedup 1.0000x reference)
//
#include <hip/hip_runtime.h>
#include <math.h>

#define N_ROWS 32768
#define D 256
#define K 1024
#define DEPTH 3
#define MARGIN 0.05f

typedef __bf16 bf16x8 __attribute__((ext_vector_type(8)));
typedef float f32x4 __attribute__((ext_vector_type(4)));
typedef __attribute__((ext_vector_type(8))) unsigned short u16x8;

// ---- ws layout (bytes) ----
// 0        idxAll[3][32768] int        -> 393216
// 393216   counts[3][1024] int         -> 405504  (memset)
// 405504   ssepart[3][2048] double     -> 454656
// 454656   e2f[3][1024] float          -> 466944
// 466944   cbp bf16 [3][1024][512]     -> 3612672
// 3612672  rp bf16 [32768][512]        -> 37167104
// 37167104 res fp32 [32768][256]       -> 70721536

__device__ __forceinline__ void gload_lds16(const void* g, void* l) {
    __builtin_amdgcn_global_load_lds(
        (const __attribute__((address_space(1))) void*)g,
        (__attribute__((address_space(3))) void*)l, 16, 0, 0);
}

__device__ __forceinline__ unsigned short f2bf(float f) {
    unsigned u = __float_as_uint(f);
    return (unsigned short)((u + 0x7fffu + ((u >> 16) & 1u)) >> 16);
}

// cbs -> packed bf16 hi|lo codebooks + e2 (fused prep)
__global__ __launch_bounds__(256) void prep_kernel(
    const float* __restrict__ cbs, unsigned short* __restrict__ cbp,
    float* __restrict__ e2f)
{
    int t = blockIdx.x * 256 + threadIdx.x;    // 98304 = 3072 rows * 32
    int row = t >> 5;
    int k8 = (t & 31) * 8;
    size_t off = (size_t)row * D + k8;
    float4 v0 = *(const float4*)(cbs + off);
    float4 v1 = *(const float4*)(cbs + off + 4);
    float v[8] = {v0.x, v0.y, v0.z, v0.w, v1.x, v1.y, v1.z, v1.w};
    u16x8 hv, lv;
    double s = 0.0;
    #pragma unroll
    for (int j = 0; j < 8; ++j) {
        unsigned short h = f2bf(v[j]);
        hv[j] = h;
        float hf = __uint_as_float(((unsigned)h) << 16);
        lv[j] = f2bf(v[j] - hf);
        s = fma((double)v[j], (double)v[j], s);
    }
    *(u16x8*)(cbp + (size_t)row * 512 + k8) = hv;
    *(u16x8*)(cbp + (size_t)row * 512 + 256 + k8) = lv;
    #pragma unroll
    for (int m = 1; m <= 16; m <<= 1) s += __shfl_xor(s, m, 32);
    if ((threadIdx.x & 31) == 0) e2f[row] = (float)s;
}

// z -> packed bf16 hi|lo rows (stage-0 residual = z)
__global__ __launch_bounds__(256) void pack_kernel(
    const float* __restrict__ src, unsigned short* __restrict__ dst)
{
    int t = blockIdx.x * 256 + threadIdx.x;
    int row = t >> 5;
    int k8 = (t & 31) * 8;
    size_t off = (size_t)row * D + k8;
    float4 v0 = *(const float4*)(src + off);
    float4 v1 = *(const float4*)(src + off + 4);
    float v[8] = {v0.x, v0.y, v0.z, v0.w, v1.x, v1.y, v1.z, v1.w};
    u16x8 hv, lv;
    #pragma unroll
    for (int j = 0; j < 8; ++j) {
        unsigned short h = f2bf(v[j]);
        hv[j] = h;
        float hf = __uint_as_float(((unsigned)h) << 16);
        lv[j] = f2bf(v[j] - hf);
    }
    *(u16x8*)(dst + (size_t)row * 512 + k8) = hv;
    *(u16x8*)(dst + (size_t)row * 512 + 256 + k8) = lv;
}

// R7 argmin body (proven 71.5us) + in-block exact fp64 refine tail reading
// the fp32 residual from global (rare rows), writing final idx directly.
__global__ __launch_bounds__(512, 2) void mfma_argmin_kernel(
    const unsigned short* __restrict__ cbp,   // [1024][512] packed bf16 (stage d)
    const unsigned short* __restrict__ rp,    // [32768][512] packed bf16
    const float* __restrict__ e2f,            // [1024] (stage d)
    const float* __restrict__ resIn,          // fp32 residual before this stage
    const float* __restrict__ cbsD,           // fp32 codebook (stage d)
    int* __restrict__ idxOut)
{
    __shared__ __align__(16) __bf16 Bsm[128 * 512];    // 128 KB resident rows
    __shared__ __align__(16) __bf16 Aw[2][256 * 32];   // 2 x 16 KB A windows

    const int tid = threadIdx.x;
    const int lane = tid & 63;
    const int w = tid >> 6;
    const int wm = w >> 1;
    const int wn = w & 1;
    const int hi = lane >> 4;
    const int lo16 = lane & 15;
    const int row0 = blockIdx.x * 128;

    // scratch carved from Aw (dead after the main loop)
    char* scr = (char*)Aw[1];
    float4* mb        = (float4*)scr;            // 8 KB merge scratch
    int*    idxS      = (int*)(scr + 8192);      // 128 ints
    int*    flagcntS  = (int*)(scr + 8704);
    int*    flaglistS = (int*)(scr + 8768);      // 32 ints
    float4* rresV     = (float4*)(scr + 9216);   // 1 KB refine residual
    double* rd8       = (double*)(scr + 10240);
    int*    ri8       = (int*)(scr + 10304);

    // ---- thread-constant addressing (identical to R7) ----
    int aPre[4], bPre[4];
    #pragma unroll
    for (int m = 0; m < 4; ++m) {
        int cl = wm * 64 + m * 16 + lo16;
        aPre[m] = cl * 64 + ((hi ^ ((cl ^ (cl >> 2)) & 3)) * 16);
    }
    #pragma unroll
    for (int n = 0; n < 4; ++n) {
        int rw = wn * 64 + n * 16 + lo16;
        bPre[n] = (rw * 1024 + hi * 16) ^ ((rw & 7) << 4);
    }
    int aSrc[2], aDst[2];
    #pragma unroll
    for (int r = 0; r < 2; ++r) {
        int q = r * 512 + tid;
        int c = q >> 2;
        int h = (q & 3) ^ ((c ^ (c >> 2)) & 3);
        aSrc[r] = c * 512 + h * 8;
        aDst[r] = q * 16;
    }

    // ---- prologue: stage resident B rows + first A window ----
    #pragma unroll
    for (int i = 0; i < 16; ++i) {
        int q = i * 512 + tid;
        int row = q >> 6, c6 = q & 63;
        gload_lds16(rp + (size_t)(row0 + row) * 512 + ((c6 ^ (row & 7)) * 8),
                    (char*)Bsm + q * 16);
    }
    #pragma unroll
    for (int r = 0; r < 2; ++r)
        gload_lds16(cbp + aSrc[r], (char*)Aw[0] + aDst[r]);

    float d1[4], d2[4];
    int   i1[4], i2[4];
    #pragma unroll
    for (int n = 0; n < 4; ++n) {
        d1[n] = 3.4e38f; d2[n] = 3.4e38f;
        i1[n] = 0x7fffffff; i2[n] = 0x7fffffff;
    }

    for (int cc = 0; cc < 4; ++cc) {
        const size_t cOff = (size_t)cc * 256 * 512;
        f32x4 acc[4][4];
        #pragma unroll
        for (int m = 0; m < 4; ++m)
            #pragma unroll
            for (int n = 0; n < 4; ++n)
                acc[m][n] = (f32x4){0.f, 0.f, 0.f, 0.f};

        for (int jp = 0; jp < 8; ++jp) {
            {   // stage LO(jp) -> buf1
                const int aOff = 256 + jp * 32;
                #pragma unroll
                for (int r = 0; r < 2; ++r)
                    gload_lds16(cbp + cOff + aOff + aSrc[r], (char*)Aw[1] + aDst[r]);
                asm volatile("s_waitcnt vmcnt(2)" ::: "memory");
            }
            __builtin_amdgcn_s_barrier();
            {
                bf16x8 af[4];
                #pragma unroll
                for (int m = 0; m < 4; ++m)
                    af[m] = *(const bf16x8*)((const char*)Aw[0] + aPre[m]);
                #pragma unroll
                for (int g = 0; g < 2; ++g) {
                    const int bOffB = (g ? 512 : 0) + jp * 64;
                    bf16x8 bfv[4];
                    #pragma unroll
                    for (int n = 0; n < 4; ++n)
                        bfv[n] = *(const bf16x8*)((const char*)Bsm + (bPre[n] ^ bOffB));
                    #pragma unroll
                    for (int m = 0; m < 4; ++m)
                        #pragma unroll
                        for (int n = 0; n < 4; ++n)
                            acc[m][n] = __builtin_amdgcn_mfma_f32_16x16x32_bf16(
                                af[m], bfv[n], acc[m][n], 0, 0, 0);
                }
            }
            __builtin_amdgcn_s_barrier();
            if (!(cc == 3 && jp == 7)) {               // stage HI(next) -> buf0
                const int jn = jp + 1;
                const size_t cOffN = cOff + (size_t)(jn >> 3) * (256 * 512);
                const int aOff = (jn & 7) * 32;
                #pragma unroll
                for (int r = 0; r < 2; ++r)
                    gload_lds16(cbp + cOffN + aOff + aSrc[r], (char*)Aw[0] + aDst[r]);
                asm volatile("s_waitcnt vmcnt(2)" ::: "memory");
            } else {
                asm volatile("s_waitcnt vmcnt(0)" ::: "memory");
            }
            __builtin_amdgcn_s_barrier();
            {
                bf16x8 af[4];
                #pragma unroll
                for (int m = 0; m < 4; ++m)
                    af[m] = *(const bf16x8*)((const char*)Aw[1] + aPre[m]);
                const int bOffB = jp * 64;
                bf16x8 bfv[4];
                #pragma unroll
                for (int n = 0; n < 4; ++n)
                    bfv[n] = *(const bf16x8*)((const char*)Bsm + (bPre[n] ^ bOffB));
                #pragma unroll
                for (int m = 0; m < 4; ++m)
                    #pragma unroll
                    for (int n = 0; n < 4; ++n)
                        acc[m][n] = __builtin_amdgcn_mfma_f32_16x16x32_bf16(
                            af[m], bfv[n], acc[m][n], 0, 0, 0);
            }
            __builtin_amdgcn_s_barrier();
        }

        // epilogue cc: dist = e2 - 2*dot; per-lane top-2 (codes ascending)
        const int cb0 = cc * 256;
        float e2a[4][4];
        #pragma unroll
        for (int m = 0; m < 4; ++m) {
            float4 t = *(const float4*)(e2f + cb0 + wm * 64 + m * 16 + hi * 4);
            e2a[m][0] = t.x; e2a[m][1] = t.y; e2a[m][2] = t.z; e2a[m][3] = t.w;
        }
        #pragma unroll
        for (int n = 0; n < 4; ++n)
            #pragma unroll
            for (int m = 0; m < 4; ++m)
                #pragma unroll
                for (int r = 0; r < 4; ++r) {
                    float dv = e2a[m][r] - 2.0f * acc[m][n][r];
                    int c = cb0 + wm * 64 + m * 16 + hi * 4 + r;
                    bool lt1 = dv < d1[n];
                    bool lt2 = dv < d2[n];
                    i2[n] = lt1 ? i1[n] : (lt2 ? c : i2[n]);
                    i1[n] = lt1 ? c : i1[n];
                    d2[n] = fminf(fmaxf(d1[n], dv), d2[n]);
                    d1[n] = fminf(d1[n], dv);
                }
    }

    // butterfly merge across the 4 hi-groups
    #pragma unroll
    for (int n = 0; n < 4; ++n) {
        #pragma unroll
        for (int mk = 0; mk < 2; ++mk) {
            int mask = mk ? 32 : 16;
            float od1 = __shfl_xor(d1[n], mask, 64);
            float od2 = __shfl_xor(d2[n], mask, 64);
            int   oi1 = __shfl_xor(i1[n], mask, 64);
            int   oi2 = __shfl_xor(i2[n], mask, 64);
            if (od1 < d1[n] || (od1 == d1[n] && oi1 < i1[n])) { d2[n] = d1[n]; i2[n] = i1[n]; d1[n] = od1; i1[n] = oi1; }
            else if (od1 < d2[n] || (od1 == d2[n] && oi1 < i2[n])) { d2[n] = od1; i2[n] = oi1; }
            if (od2 < d1[n] || (od2 == d1[n] && oi2 < i1[n])) { d2[n] = d1[n]; i2[n] = i1[n]; d1[n] = od2; i1[n] = oi2; }
            else if (od2 < d2[n] || (od2 == d2[n] && oi2 < i2[n])) { d2[n] = od2; i2[n] = oi2; }
        }
    }

    __syncthreads();                // all waves done with Aw reads
    if (tid == 0) *flagcntS = 0;
    if (lane < 16) {
        #pragma unroll
        for (int n = 0; n < 4; ++n)
            mb[wm * 128 + wn * 64 + n * 16 + lo16] =
                make_float4(d1[n], d2[n], __int_as_float(i1[n]), __int_as_float(i2[n]));
    }
    __syncthreads();
    if (tid < 128) {
        float fd1 = 3.4e38f, fd2 = 3.4e38f;
        int   fi1 = 0x7fffffff, fi2 = 0x7fffffff;
        #pragma unroll
        for (int pc = 0; pc < 4; ++pc) {
            float4 p = mb[pc * 128 + tid];
            float pd1 = p.x, pd2 = p.y;
            int   pi1 = __float_as_int(p.z), pi2 = __float_as_int(p.w);
            if (pd1 < fd1 || (pd1 == fd1 && pi1 < fi1)) { fd2 = fd1; fi2 = fi1; fd1 = pd1; fi1 = pi1; }
            else if (pd1 < fd2 || (pd1 == fd2 && pi1 < fi2)) { fd2 = pd1; fi2 = pi1; }
            if (pd2 < fd1 || (pd2 == fd1 && pi2 < fi1)) { fd2 = fd1; fi2 = fi1; fd1 = pd2; fi1 = pi2; }
            else if (pd2 < fd2 || (pd2 == fd2 && pi2 < fi2)) { fd2 = pd2; fi2 = pi2; }
        }
        idxS[tid] = fi1;
        if (fd2 - fd1 < MARGIN) {
            int pos = atomicAdd(flagcntS, 1);
            if (pos < 32) flaglistS[pos] = tid;
        }
    }
    __syncthreads();

    // ---- in-block exact fp64 refine (rare rows), residual from global ----
    int cnt = *flagcntS;
    if (cnt > 32) cnt = 32;
    for (int f = 0; f < cnt; ++f) {
        int lr = flaglistS[f];
        if (tid < 64)
            rresV[tid] = ((const float4*)(resIn + (size_t)(row0 + lr) * D))[tid];
        __syncthreads();
        double best = 1e300; int bi = 0;
        #pragma unroll
        for (int cd = 0; cd < 2; ++cd) {
            int c = tid * 2 + cd;
            const float4* cp = (const float4*)(cbsD + (size_t)c * D);
            double s = 0.0;
            for (int k = 0; k < 64; ++k) {
                float4 cv = cp[k];
                float4 rv = rresV[k];
                double a0 = (double)rv.x - (double)cv.x; s = fma(a0, a0, s);
                double a1 = (double)rv.y - (double)cv.y; s = fma(a1, a1, s);
                double a2 = (double)rv.z - (double)cv.z; s = fma(a2, a2, s);
                double a3 = (double)rv.w - (double)cv.w; s = fma(a3, a3, s);
            }
            if (s < best || (s == best && c < bi)) { best = s; bi = c; }
        }
        #pragma unroll
        for (int m = 1; m <= 32; m <<= 1) {
            double od = __shfl_xor(best, m, 64);
            int oi = __shfl_xor(bi, m, 64);
            if (od < best || (od == best && oi < bi)) { best = od; bi = oi; }
        }
        if (lane == 0) { rd8[w] = best; ri8[w] = bi; }
        __syncthreads();
        if (tid == 0) {
            double bb = rd8[0]; int bj = ri8[0];
            for (int ww = 1; ww < 8; ++ww)
                if (rd8[ww] < bb || (rd8[ww] == bb && ri8[ww] < bj)) { bb = rd8[ww]; bj = ri8[ww]; }
            idxS[lr] = bj;
        }
        __syncthreads();
    }

    if (tid < 128) idxOut[row0 + tid] = idxS[tid];
}

// update: r = in - cb[idx] (exact reference fp32 chain); write res or qtot=z-r;
// pack rp for next stage; SSE partial per block; counts.
__global__ __launch_bounds__(256) void update_kernel(
    const float* __restrict__ in, const float* __restrict__ z,
    float* __restrict__ resOut, float* __restrict__ qtotOut,
    const float* __restrict__ cbD, const int* __restrict__ idxStage,
    unsigned short* __restrict__ rpOut, int* __restrict__ counts,
    double* __restrict__ ssepart, int lastD)
{
    double s = 0.0;
    const int base = blockIdx.x * 256 + threadIdx.x;
    #pragma unroll
    for (int it = 0; it < 4; ++it) {
        int t = base + it * 524288;            // quad id over N_ROWS*64
        int row = t >> 6;
        int c4  = (t & 63) << 2;
        int idx = idxStage[row];
        size_t off = (size_t)row * D + c4;
        float4 iv = *(const float4*)(in + off);
        float4 cv = *(const float4*)(cbD + (size_t)idx * D + c4);
        float4 r;
        r.x = iv.x - cv.x; r.y = iv.y - cv.y;
        r.z = iv.z - cv.z; r.w = iv.w - cv.w;
        if (lastD) {
            float4 zv = *(const float4*)(z + off);
            float4 q;
            q.x = zv.x - r.x; q.y = zv.y - r.y;
            q.z = zv.z - r.z; q.w = zv.w - r.w;
            *(float4*)(qtotOut + off) = q;
        } else {
            *(float4*)(resOut + off) = r;
            float rv[4] = {r.x, r.y, r.z, r.w};
            ushort4 hv, lv;
            ushort* hp = (ushort*)&hv; ushort* lp = (ushort*)&lv;
            #pragma unroll
            for (int j = 0; j < 4; ++j) {
                unsigned short h = f2bf(rv[j]);
                hp[j] = h;
                float hf = __uint_as_float(((unsigned)h) << 16);
                lp[j] = f2bf(rv[j] - hf);
            }
            *(ushort4*)(rpOut + (size_t)row * 512 + c4) = hv;
            *(ushort4*)(rpOut + (size_t)row * 512 + 256 + c4) = lv;
        }
        s = fma((double)r.x, (double)r.x, s);
        s = fma((double)r.y, (double)r.y, s);
        s = fma((double)r.z, (double)r.z, s);
        s = fma((double)r.w, (double)r.w, s);
        if ((t & 63) == 0) atomicAdd(counts + idx, 1);
    }
    for (int o = 32; o > 0; o >>= 1) s += __shfl_down(s, o, 64);
    __shared__ double wsum[4];
    int lane = threadIdx.x & 63, wv = threadIdx.x >> 6;
    if (lane == 0) wsum[wv] = s;
    __syncthreads();
    if (threadIdx.x == 0)
        ssepart[blockIdx.x] = wsum[0] + wsum[1] + wsum[2] + wsum[3];
}

// compose + perplexity + loss
__global__ void final_kernel(const int* __restrict__ idxAll, const int* __restrict__ counts,
                             const double* __restrict__ ssepart,
                             float* __restrict__ loss, float* __restrict__ comp,
                             float* __restrict__ perps)
{
    __shared__ double red[16];
    __shared__ double lossAcc;
    const int tid = threadIdx.x;   // 1024 threads
    for (int n = tid; n < N_ROWS; n += 1024) {
        int v = idxAll[n] + (idxAll[N_ROWS + n] << 10) + (idxAll[2 * N_ROWS + n] << 20);
        comp[n] = (float)v;
    }
    if (tid == 0) lossAcc = 0.0;
    __syncthreads();
    for (int d = 0; d < DEPTH; ++d) {
        double p = (double)counts[d * K + tid] / 32768.0;
        double s = p * log(p + 1e-10);
        double q = ssepart[d * 2048 + tid] + ssepart[d * 2048 + 1024 + tid];
        for (int o = 32; o > 0; o >>= 1) {
            s += __shfl_down(s, o, 64);
            q += __shfl_down(q, o, 64);
        }
        if ((tid & 63) == 0) red[tid >> 6] = s;
        __syncthreads();
        if (tid == 0) {
            double tot = 0.0;
            for (int i = 0; i < 16; ++i) tot += red[i];
            perps[d] = (float)exp(-tot);
        }
        __syncthreads();
        if ((tid & 63) == 0) red[tid >> 6] = q;
        __syncthreads();
        if (tid == 0) {
            double tq = 0.0;
            for (int i = 0; i < 16; ++i) tq += red[i];
            lossAcc += tq;
        }
        __syncthreads();
    }
    if (tid == 0)
        loss[0] = (float)(1.25 * lossAcc / 8388608.0);
}

extern "C" void kernel_launch(void* const* d_in, const int* in_sizes, int n_in,
                              void* d_out, int out_size, void* d_ws, size_t ws_size,
                              hipStream_t stream)
{
    const float* z   = (const float*)d_in[0];
    const float* cbs = (const float*)d_in[1];
    float* out = (float*)d_out;
    char*  ws  = (char*)d_ws;

    int*            idxAll   = (int*)ws;
    int*            counts   = (int*)(ws + 393216);
    double*         ssepart  = (double*)(ws + 405504);
    float*          e2f      = (float*)(ws + 454656);
    unsigned short* cbp      = (unsigned short*)(ws + 466944);
    unsigned short* rp       = (unsigned short*)(ws + 3612672);
    float*          res      = (float*)(ws + 37167104);

    float* qtot  = out;                       // 8388608 elems
    float* loss  = out + 8388608;             // 1
    float* comp  = out + 8388609;             // 32768
    float* perps = out + 8388609 + 32768;     // 3

    hipMemsetAsync(counts, 0, 12288, stream);

    prep_kernel<<<384, 256, 0, stream>>>(cbs, cbp, e2f);
    pack_kernel<<<4096, 256, 0, stream>>>(z, rp);    // stage-0 residual = z

    for (int d = 0; d < DEPTH; ++d) {
        const float* cbD = cbs + (size_t)d * K * D;
        const float* resIn = (d == 0) ? z : res;
        int lastD = (d == DEPTH - 1) ? 1 : 0;
        mfma_argmin_kernel<<<256, 512, 0, stream>>>(
            cbp + (size_t)d * K * 512, rp, e2f + d * K, resIn, cbD,
            idxAll + d * N_ROWS);
        update_kernel<<<2048, 256, 0, stream>>>(
            resIn, z, res, qtot, cbD, idxAll + d * N_ROWS, rp,
            counts + d * K, ssepart + d * 2048, lastD);
    }

    final_kernel<<<1, 1024, 0, stream>>>(idxAll, counts, ssepart, loss, comp, perps);
}

// Round 10
// 417.884 us; speedup vs baseline: 1.4159x; 1.4159x over previous
//
#include <hip/hip_runtime.h>
#include <math.h>

#define N_ROWS 32768
#define D 256
#define K 1024
#define DEPTH 3
#define MARGIN 0.016f

typedef __bf16 bf16x8 __attribute__((ext_vector_type(8)));
typedef float f32x4 __attribute__((ext_vector_type(4)));
typedef __attribute__((ext_vector_type(8))) unsigned short u16x8;

// ---- ws layout (bytes) ----
// 0        idxAll[3][32768] int        -> 393216
// 393216   counts[3][1024] int         -> 405504  (memset)
// 405504   flagcnt[3] int (pad)        -> 405520  (memset)
// 405520   flaglist[32768] int         -> 536592
// 536592   ssepart[3][2048] double     -> 585744
// 585744   e2f[3][1024] float          -> 598032 (pad 598080)
// 598080   cbp bf16 [3][1024][512]     -> 3743808
// 3743808  rp bf16 [32768][512]        -> 37298240
// 37298240 res fp32 [32768][256]       -> 70852672

__device__ __forceinline__ void gload_lds16(const void* g, void* l) {
    __builtin_amdgcn_global_load_lds(
        (const __attribute__((address_space(1))) void*)g,
        (__attribute__((address_space(3))) void*)l, 16, 0, 0);
}

__device__ __forceinline__ unsigned short f2bf(float f) {
    unsigned u = __float_as_uint(f);
    return (unsigned short)((u + 0x7fffu + ((u >> 16) & 1u)) >> 16);
}

// cbs -> packed bf16 hi|lo codebooks + e2 (fused prep)
__global__ __launch_bounds__(256) void prep_kernel(
    const float* __restrict__ cbs, unsigned short* __restrict__ cbp,
    float* __restrict__ e2f)
{
    int t = blockIdx.x * 256 + threadIdx.x;    // 98304 = 3072 rows * 32
    int row = t >> 5;
    int k8 = (t & 31) * 8;
    size_t off = (size_t)row * D + k8;
    float4 v0 = *(const float4*)(cbs + off);
    float4 v1 = *(const float4*)(cbs + off + 4);
    float v[8] = {v0.x, v0.y, v0.z, v0.w, v1.x, v1.y, v1.z, v1.w};
    u16x8 hv, lv;
    double s = 0.0;
    #pragma unroll
    for (int j = 0; j < 8; ++j) {
        unsigned short h = f2bf(v[j]);
        hv[j] = h;
        float hf = __uint_as_float(((unsigned)h) << 16);
        lv[j] = f2bf(v[j] - hf);
        s = fma((double)v[j], (double)v[j], s);
    }
    *(u16x8*)(cbp + (size_t)row * 512 + k8) = hv;
    *(u16x8*)(cbp + (size_t)row * 512 + 256 + k8) = lv;
    #pragma unroll
    for (int m = 1; m <= 16; m <<= 1) s += __shfl_xor(s, m, 32);
    if ((threadIdx.x & 31) == 0) e2f[row] = (float)s;
}

// z -> packed bf16 hi|lo rows (stage-0 residual = z)
__global__ __launch_bounds__(256) void pack_kernel(
    const float* __restrict__ src, unsigned short* __restrict__ dst)
{
    int t = blockIdx.x * 256 + threadIdx.x;
    int row = t >> 5;
    int k8 = (t & 31) * 8;
    size_t off = (size_t)row * D + k8;
    float4 v0 = *(const float4*)(src + off);
    float4 v1 = *(const float4*)(src + off + 4);
    float v[8] = {v0.x, v0.y, v0.z, v0.w, v1.x, v1.y, v1.z, v1.w};
    u16x8 hv, lv;
    #pragma unroll
    for (int j = 0; j < 8; ++j) {
        unsigned short h = f2bf(v[j]);
        hv[j] = h;
        float hf = __uint_as_float(((unsigned)h) << 16);
        lv[j] = f2bf(v[j] - hf);
    }
    *(u16x8*)(dst + (size_t)row * 512 + k8) = hv;
    *(u16x8*)(dst + (size_t)row * 512 + 256 + k8) = lv;
}

// R7-proven argmin: 8 waves, 128 rows resident, A windows double-buffered
// with counted vmcnt(2). Writes argmin + near-tie flags to global.
__global__ __launch_bounds__(512, 2) void mfma_argmin_kernel(
    const unsigned short* __restrict__ cbp,   // [1024][512] packed bf16 (stage d)
    const unsigned short* __restrict__ rp,    // [32768][512] packed bf16
    const float* __restrict__ e2f,            // [1024] (stage d)
    int* __restrict__ idxOut, int* __restrict__ flagcnt, int* __restrict__ flaglist)
{
    __shared__ __align__(16) __bf16 Bsm[128 * 512];    // 128 KB resident rows
    __shared__ __align__(16) __bf16 Aw[2][256 * 32];   // 2 x 16 KB A windows

    const int tid = threadIdx.x;
    const int lane = tid & 63;
    const int w = tid >> 6;
    const int wm = w >> 1;
    const int wn = w & 1;
    const int hi = lane >> 4;
    const int lo16 = lane & 15;
    const int row0 = blockIdx.x * 128;

    int aPre[4], bPre[4];
    #pragma unroll
    for (int m = 0; m < 4; ++m) {
        int cl = wm * 64 + m * 16 + lo16;
        aPre[m] = cl * 64 + ((hi ^ ((cl ^ (cl >> 2)) & 3)) * 16);
    }
    #pragma unroll
    for (int n = 0; n < 4; ++n) {
        int rw = wn * 64 + n * 16 + lo16;
        bPre[n] = (rw * 1024 + hi * 16) ^ ((rw & 7) << 4);
    }
    int aSrc[2], aDst[2];
    #pragma unroll
    for (int r = 0; r < 2; ++r) {
        int q = r * 512 + tid;
        int c = q >> 2;
        int h = (q & 3) ^ ((c ^ (c >> 2)) & 3);
        aSrc[r] = c * 512 + h * 8;
        aDst[r] = q * 16;
    }

    // prologue: stage resident B rows + first A window
    #pragma unroll
    for (int i = 0; i < 16; ++i) {
        int q = i * 512 + tid;
        int row = q >> 6, c6 = q & 63;
        gload_lds16(rp + (size_t)(row0 + row) * 512 + ((c6 ^ (row & 7)) * 8),
                    (char*)Bsm + q * 16);
    }
    #pragma unroll
    for (int r = 0; r < 2; ++r)
        gload_lds16(cbp + aSrc[r], (char*)Aw[0] + aDst[r]);

    float d1[4], d2[4];
    int   i1[4], i2[4];
    #pragma unroll
    for (int n = 0; n < 4; ++n) {
        d1[n] = 3.4e38f; d2[n] = 3.4e38f;
        i1[n] = 0x7fffffff; i2[n] = 0x7fffffff;
    }

    for (int cc = 0; cc < 4; ++cc) {
        const size_t cOff = (size_t)cc * 256 * 512;
        f32x4 acc[4][4];
        #pragma unroll
        for (int m = 0; m < 4; ++m)
            #pragma unroll
            for (int n = 0; n < 4; ++n)
                acc[m][n] = (f32x4){0.f, 0.f, 0.f, 0.f};

        for (int jp = 0; jp < 8; ++jp) {
            {   // stage LO(jp) -> buf1
                const int aOff = 256 + jp * 32;
                #pragma unroll
                for (int r = 0; r < 2; ++r)
                    gload_lds16(cbp + cOff + aOff + aSrc[r], (char*)Aw[1] + aDst[r]);
                asm volatile("s_waitcnt vmcnt(2)" ::: "memory");
            }
            __builtin_amdgcn_s_barrier();
            {
                bf16x8 af[4];
                #pragma unroll
                for (int m = 0; m < 4; ++m)
                    af[m] = *(const bf16x8*)((const char*)Aw[0] + aPre[m]);
                #pragma unroll
                for (int g = 0; g < 2; ++g) {
                    const int bOffB = (g ? 512 : 0) + jp * 64;
                    bf16x8 bfv[4];
                    #pragma unroll
                    for (int n = 0; n < 4; ++n)
                        bfv[n] = *(const bf16x8*)((const char*)Bsm + (bPre[n] ^ bOffB));
                    #pragma unroll
                    for (int m = 0; m < 4; ++m)
                        #pragma unroll
                        for (int n = 0; n < 4; ++n)
                            acc[m][n] = __builtin_amdgcn_mfma_f32_16x16x32_bf16(
                                af[m], bfv[n], acc[m][n], 0, 0, 0);
                }
            }
            __builtin_amdgcn_s_barrier();
            if (!(cc == 3 && jp == 7)) {               // stage HI(next) -> buf0
                const int jn = jp + 1;
                const size_t cOffN = cOff + (size_t)(jn >> 3) * (256 * 512);
                const int aOff = (jn & 7) * 32;
                #pragma unroll
                for (int r = 0; r < 2; ++r)
                    gload_lds16(cbp + cOffN + aOff + aSrc[r], (char*)Aw[0] + aDst[r]);
                asm volatile("s_waitcnt vmcnt(2)" ::: "memory");
            } else {
                asm volatile("s_waitcnt vmcnt(0)" ::: "memory");
            }
            __builtin_amdgcn_s_barrier();
            {
                bf16x8 af[4];
                #pragma unroll
                for (int m = 0; m < 4; ++m)
                    af[m] = *(const bf16x8*)((const char*)Aw[1] + aPre[m]);
                const int bOffB = jp * 64;
                bf16x8 bfv[4];
                #pragma unroll
                for (int n = 0; n < 4; ++n)
                    bfv[n] = *(const bf16x8*)((const char*)Bsm + (bPre[n] ^ bOffB));
                #pragma unroll
                for (int m = 0; m < 4; ++m)
                    #pragma unroll
                    for (int n = 0; n < 4; ++n)
                        acc[m][n] = __builtin_amdgcn_mfma_f32_16x16x32_bf16(
                            af[m], bfv[n], acc[m][n], 0, 0, 0);
            }
            __builtin_amdgcn_s_barrier();
        }

        // epilogue cc: dist = e2 - 2*dot; per-lane top-2 (codes ascending)
        const int cb0 = cc * 256;
        float e2a[4][4];
        #pragma unroll
        for (int m = 0; m < 4; ++m) {
            float4 t = *(const float4*)(e2f + cb0 + wm * 64 + m * 16 + hi * 4);
            e2a[m][0] = t.x; e2a[m][1] = t.y; e2a[m][2] = t.z; e2a[m][3] = t.w;
        }
        #pragma unroll
        for (int n = 0; n < 4; ++n)
            #pragma unroll
            for (int m = 0; m < 4; ++m)
                #pragma unroll
                for (int r = 0; r < 4; ++r) {
                    float dv = e2a[m][r] - 2.0f * acc[m][n][r];
                    int c = cb0 + wm * 64 + m * 16 + hi * 4 + r;
                    bool lt1 = dv < d1[n];
                    bool lt2 = dv < d2[n];
                    i2[n] = lt1 ? i1[n] : (lt2 ? c : i2[n]);
                    i1[n] = lt1 ? c : i1[n];
                    d2[n] = fminf(fmaxf(d1[n], dv), d2[n]);
                    d1[n] = fminf(d1[n], dv);
                }
    }

    // butterfly merge across the 4 hi-groups
    #pragma unroll
    for (int n = 0; n < 4; ++n) {
        #pragma unroll
        for (int mk = 0; mk < 2; ++mk) {
            int mask = mk ? 32 : 16;
            float od1 = __shfl_xor(d1[n], mask, 64);
            float od2 = __shfl_xor(d2[n], mask, 64);
            int   oi1 = __shfl_xor(i1[n], mask, 64);
            int   oi2 = __shfl_xor(i2[n], mask, 64);
            if (od1 < d1[n] || (od1 == d1[n] && oi1 < i1[n])) { d2[n] = d1[n]; i2[n] = i1[n]; d1[n] = od1; i1[n] = oi1; }
            else if (od1 < d2[n] || (od1 == d2[n] && oi1 < i2[n])) { d2[n] = od1; i2[n] = oi1; }
            if (od2 < d1[n] || (od2 == d1[n] && oi2 < i1[n])) { d2[n] = d1[n]; i2[n] = i1[n]; d1[n] = od2; i1[n] = oi2; }
            else if (od2 < d2[n] || (od2 == d2[n] && oi2 < i2[n])) { d2[n] = od2; i2[n] = oi2; }
        }
    }

    // cross-wave merge via LDS scratch (A buffers dead after last barrier)
    float4* mb = (float4*)Aw;      // 512 float4 = 8 KB scratch
    if (lane < 16) {
        #pragma unroll
        for (int n = 0; n < 4; ++n)
            mb[wm * 128 + wn * 64 + n * 16 + lo16] =
                make_float4(d1[n], d2[n], __int_as_float(i1[n]), __int_as_float(i2[n]));
    }
    __syncthreads();
    if (tid < 128) {
        float fd1 = 3.4e38f, fd2 = 3.4e38f;
        int   fi1 = 0x7fffffff, fi2 = 0x7fffffff;
        #pragma unroll
        for (int pc = 0; pc < 4; ++pc) {
            float4 p = mb[pc * 128 + tid];
            float pd1 = p.x, pd2 = p.y;
            int   pi1 = __float_as_int(p.z), pi2 = __float_as_int(p.w);
            if (pd1 < fd1 || (pd1 == fd1 && pi1 < fi1)) { fd2 = fd1; fi2 = fi1; fd1 = pd1; fi1 = pi1; }
            else if (pd1 < fd2 || (pd1 == fd2 && pi1 < fi2)) { fd2 = pd1; fi2 = pi1; }
            if (pd2 < fd1 || (pd2 == fd1 && pi2 < fi1)) { fd2 = fd1; fi2 = fi1; fd1 = pd2; fi1 = pi2; }
            else if (pd2 < fd2 || (pd2 == fd2 && pi2 < fi2)) { fd2 = pd2; fi2 = pi2; }
        }
        int row = row0 + tid;
        idxOut[row] = fi1;
        if (fd2 - fd1 < MARGIN) {
            int pos = atomicAdd(flagcnt, 1);
            if (pos < N_ROWS) flaglist[pos] = row;
        }
    }
}

// Exact fp64 re-rank for near-tie rows; residual read directly; ILP4 chains.
__global__ __launch_bounds__(256) void refine_kernel(
    const float* __restrict__ resIn, const float* __restrict__ cbsD,
    int* __restrict__ idxOut,
    const int* __restrict__ flagcnt, const int* __restrict__ flaglist)
{
    __shared__ float4 rres[64];
    __shared__ double bd[256];
    __shared__ int    bidx[256];
    const int tid = threadIdx.x;
    int cnt = *flagcnt;
    if (cnt > N_ROWS) cnt = N_ROWS;
    for (int f = blockIdx.x; f < cnt; f += gridDim.x) {
        int row = flaglist[f];
        __syncthreads();
        if (tid < 64)
            rres[tid] = ((const float4*)(resIn + (size_t)row * D))[tid];
        __syncthreads();
        double best = 1e300; int bi = 0;
        for (int j = 0; j < 4; ++j) {
            int c = tid * 4 + j;
            const float4* cp = (const float4*)(cbsD + (size_t)c * D);
            double s0 = 0.0, s1 = 0.0, s2 = 0.0, s3 = 0.0;
            for (int k = 0; k < 16; ++k) {
                float4 c0 = cp[k], c1 = cp[k + 16], c2 = cp[k + 32], c3 = cp[k + 48];
                float4 r0 = rres[k], r1 = rres[k + 16], r2 = rres[k + 32], r3 = rres[k + 48];
                double a;
                a = (double)r0.x - (double)c0.x; s0 = fma(a, a, s0);
                a = (double)r0.y - (double)c0.y; s0 = fma(a, a, s0);
                a = (double)r0.z - (double)c0.z; s0 = fma(a, a, s0);
                a = (double)r0.w - (double)c0.w; s0 = fma(a, a, s0);
                a = (double)r1.x - (double)c1.x; s1 = fma(a, a, s1);
                a = (double)r1.y - (double)c1.y; s1 = fma(a, a, s1);
                a = (double)r1.z - (double)c1.z; s1 = fma(a, a, s1);
                a = (double)r1.w - (double)c1.w; s1 = fma(a, a, s1);
                a = (double)r2.x - (double)c2.x; s2 = fma(a, a, s2);
                a = (double)r2.y - (double)c2.y; s2 = fma(a, a, s2);
                a = (double)r2.z - (double)c2.z; s2 = fma(a, a, s2);
                a = (double)r2.w - (double)c2.w; s2 = fma(a, a, s2);
                a = (double)r3.x - (double)c3.x; s3 = fma(a, a, s3);
                a = (double)r3.y - (double)c3.y; s3 = fma(a, a, s3);
                a = (double)r3.z - (double)c3.z; s3 = fma(a, a, s3);
                a = (double)r3.w - (double)c3.w; s3 = fma(a, a, s3);
            }
            double s = (s0 + s1) + (s2 + s3);
            if (s < best || (s == best && c < bi)) { best = s; bi = c; }
        }
        bd[tid] = best; bidx[tid] = bi;
        __syncthreads();
        for (int off = 128; off > 0; off >>= 1) {
            if (tid < off) {
                if (bd[tid + off] < bd[tid] ||
                    (bd[tid + off] == bd[tid] && bidx[tid + off] < bidx[tid])) {
                    bd[tid] = bd[tid + off]; bidx[tid] = bidx[tid + off];
                }
            }
            __syncthreads();
        }
        if (tid == 0) idxOut[row] = bidx[0];
        __syncthreads();
    }
}

// update: r = in - cb[idx]; write res or qtot=z-r; pack rp; SSE; counts.
__global__ __launch_bounds__(256) void update_kernel(
    const float* __restrict__ in, const float* __restrict__ z,
    float* __restrict__ resOut, float* __restrict__ qtotOut,
    const float* __restrict__ cbD, const int* __restrict__ idxStage,
    unsigned short* __restrict__ rpOut, int* __restrict__ counts,
    double* __restrict__ ssepart, int lastD)
{
    double s = 0.0;
    const int base = blockIdx.x * 256 + threadIdx.x;
    #pragma unroll
    for (int it = 0; it < 4; ++it) {
        int t = base + it * 524288;            // quad id over N_ROWS*64
        int row = t >> 6;
        int c4  = (t & 63) << 2;
        int idx = idxStage[row];
        size_t off = (size_t)row * D + c4;
        float4 iv = *(const float4*)(in + off);
        float4 cv = *(const float4*)(cbD + (size_t)idx * D + c4);
        float4 r;
        r.x = iv.x - cv.x; r.y = iv.y - cv.y;
        r.z = iv.z - cv.z; r.w = iv.w - cv.w;
        if (lastD) {
            float4 zv = *(const float4*)(z + off);
            float4 q;
            q.x = zv.x - r.x; q.y = zv.y - r.y;
            q.z = zv.z - r.z; q.w = zv.w - r.w;
            *(float4*)(qtotOut + off) = q;
        } else {
            *(float4*)(resOut + off) = r;
            float rv[4] = {r.x, r.y, r.z, r.w};
            ushort4 hv, lv;
            ushort* hp = (ushort*)&hv; ushort* lp = (ushort*)&lv;
            #pragma unroll
            for (int j = 0; j < 4; ++j) {
                unsigned short h = f2bf(rv[j]);
                hp[j] = h;
                float hf = __uint_as_float(((unsigned)h) << 16);
                lp[j] = f2bf(rv[j] - hf);
            }
            *(ushort4*)(rpOut + (size_t)row * 512 + c4) = hv;
            *(ushort4*)(rpOut + (size_t)row * 512 + 256 + c4) = lv;
        }
        s = fma((double)r.x, (double)r.x, s);
        s = fma((double)r.y, (double)r.y, s);
        s = fma((double)r.z, (double)r.z, s);
        s = fma((double)r.w, (double)r.w, s);
        if ((t & 63) == 0) atomicAdd(counts + idx, 1);
    }
    for (int o = 32; o > 0; o >>= 1) s += __shfl_down(s, o, 64);
    __shared__ double wsum[4];
    int lane = threadIdx.x & 63, wv = threadIdx.x >> 6;
    if (lane == 0) wsum[wv] = s;
    __syncthreads();
    if (threadIdx.x == 0)
        ssepart[blockIdx.x] = wsum[0] + wsum[1] + wsum[2] + wsum[3];
}

// compose + perplexity + loss
__global__ void final_kernel(const int* __restrict__ idxAll, const int* __restrict__ counts,
                             const double* __restrict__ ssepart,
                             float* __restrict__ loss, float* __restrict__ comp,
                             float* __restrict__ perps)
{
    __shared__ double red[16];
    __shared__ double lossAcc;
    const int tid = threadIdx.x;   // 1024 threads
    for (int n = tid; n < N_ROWS; n += 1024) {
        int v = idxAll[n] + (idxAll[N_ROWS + n] << 10) + (idxAll[2 * N_ROWS + n] << 20);
        comp[n] = (float)v;
    }
    if (tid == 0) lossAcc = 0.0;
    __syncthreads();
    for (int d = 0; d < DEPTH; ++d) {
        double p = (double)counts[d * K + tid] / 32768.0;
        double s = p * log(p + 1e-10);
        double q = ssepart[d * 2048 + tid] + ssepart[d * 2048 + 1024 + tid];
        for (int o = 32; o > 0; o >>= 1) {
            s += __shfl_down(s, o, 64);
            q += __shfl_down(q, o, 64);
        }
        if ((tid & 63) == 0) red[tid >> 6] = s;
        __syncthreads();
        if (tid == 0) {
            double tot = 0.0;
            for (int i = 0; i < 16; ++i) tot += red[i];
            perps[d] = (float)exp(-tot);
        }
        __syncthreads();
        if ((tid & 63) == 0) red[tid >> 6] = q;
        __syncthreads();
        if (tid == 0) {
            double tq = 0.0;
            for (int i = 0; i < 16; ++i) tq += red[i];
            lossAcc += tq;
        }
        __syncthreads();
    }
    if (tid == 0)
        loss[0] = (float)(1.25 * lossAcc / 8388608.0);
}

extern "C" void kernel_launch(void* const* d_in, const int* in_sizes, int n_in,
                              void* d_out, int out_size, void* d_ws, size_t ws_size,
                              hipStream_t stream)
{
    const float* z   = (const float*)d_in[0];
    const float* cbs = (const float*)d_in[1];
    float* out = (float*)d_out;
    char*  ws  = (char*)d_ws;

    int*            idxAll   = (int*)ws;
    int*            counts   = (int*)(ws + 393216);
    int*            flagcnt  = (int*)(ws + 405504);
    int*            flaglist = (int*)(ws + 405520);
    double*         ssepart  = (double*)(ws + 536592);
    float*          e2f      = (float*)(ws + 585744);
    unsigned short* cbp      = (unsigned short*)(ws + 598080);
    unsigned short* rp       = (unsigned short*)(ws + 3743808);
    float*          res      = (float*)(ws + 37298240);

    float* qtot  = out;                       // 8388608 elems
    float* loss  = out + 8388608;             // 1
    float* comp  = out + 8388609;             // 32768
    float* perps = out + 8388609 + 32768;     // 3

    hipMemsetAsync(ws + 393216, 0, 405520 - 393216, stream);  // counts + flagcnt

    prep_kernel<<<384, 256, 0, stream>>>(cbs, cbp, e2f);
    pack_kernel<<<4096, 256, 0, stream>>>(z, rp);    // stage-0 residual = z

    for (int d = 0; d < DEPTH; ++d) {
        const float* cbD = cbs + (size_t)d * K * D;
        const float* resIn = (d == 0) ? z : res;
        int lastD = (d == DEPTH - 1) ? 1 : 0;
        mfma_argmin_kernel<<<256, 512, 0, stream>>>(
            cbp + (size_t)d * K * 512, rp, e2f + d * K,
            idxAll + d * N_ROWS, flagcnt + d, flaglist);
        refine_kernel<<<256, 256, 0, stream>>>(
            resIn, cbD, idxAll + d * N_ROWS, flagcnt + d, flaglist);
        update_kernel<<<2048, 256, 0, stream>>>(
            resIn, z, res, qtot, cbD, idxAll + d * N_ROWS, rp,
            counts + d * K, ssepart + d * 2048, lastD);
    }

    final_kernel<<<1, 1024, 0, stream>>>(idxAll, counts, ssepart, loss, comp, perps);
}